// Round 10
// baseline (62.407 us; speedup 1.0000x reference)
//
#include <hip/hip_runtime.h>
#include <math.h>

#define HIDDEN 128
#define NGRAPH 16384
#define GPB 32                  // graphs per block
#define NBLK (NGRAPH / GPB)     // 512 blocks
#define NTHR 512                // 8 waves/block; 2 blocks/CU = 16 waves/CU

typedef __attribute__((ext_vector_type(8))) short short8;   // 8 bf16
typedef __attribute__((ext_vector_type(4))) float f32x4;    // MFMA accum

// shifted-softplus shift = log(2)
__device__ __constant__ float kSHIFT = 0.69314718055994530942f;

// fp32 -> bf16 (RNE), bit-level
__device__ __forceinline__ unsigned short f2bf(float f) {
    unsigned int u = __builtin_bit_cast(unsigned int, f);
    u = (u + 0x7FFFu + ((u >> 16) & 1u)) >> 16;
    return (unsigned short)u;
}

// ---------------------------------------------------------------------------
// Kernel 0: boundary scan. batch sorted; thread i writes offs[g]=i for every
// graph g starting at i (covers empty graphs). offs[NGRAPH]=n_nodes.
// ---------------------------------------------------------------------------
__global__ __launch_bounds__(256) void offsets_kernel(
    const int* __restrict__ batch, int* __restrict__ offs, int n_nodes)
{
    int i = blockIdx.x * blockDim.x + threadIdx.x;
    if (i >= n_nodes) return;
    int b = batch[i];
    int prev = (i == 0) ? -1 : batch[i - 1];
    for (int g = prev + 1; g <= b; ++g) offs[g] = i;        // rare
    if (i == n_nodes - 1)
        for (int g = b + 1; g <= NGRAPH; ++g) offs[g] = n_nodes;
}

// ---------------------------------------------------------------------------
// Fused kernel: 512 blocks x 512 threads (8 waves), 32 graphs/block.
// Phase 1 (BALANCED): the block's row range [offs[g0], offs[g0+32]) is split
//   into 8 EQUAL chunks, one per wave (waves perfectly balanced; only the
//   ~3% block-level variance remains). Each wave streams its chunk with
//   8-row straight-line float2 load blocks, accumulates the current graph's
//   run in registers, and flushes runs into a fp32 LDS accumulator with
//   ds_add_f32 atomics (graphs split across chunks get two flushes).
// Convert: u_s fp32 -> u_b bf16, XOR-swizzled rows (one tiny pass).
// Phase 2 (unchanged from R8): B-frags of W1 in registers (loaded once,
//   global), 16 x v_mfma_f32_16x16x32_bf16 per wave, conflict-free swizzled
//   ds_read_b128 A-frags. Epilogue: bias -> shifted softplus -> *W2 ->
//   16-lane shfl reduce -> cross-wave LDS reduce.
// LDS: 16 KB u_s + 8 KB u_b + 1 KB red + offs = ~25.2 KB -> 2 blocks/CU.
// ---------------------------------------------------------------------------
__global__ __launch_bounds__(NTHR, 4) void fused_kernel(
    const float* __restrict__ v, const int* __restrict__ offs,
    const float* __restrict__ W1, const float* __restrict__ b1,
    const float* __restrict__ W2, const float* __restrict__ b2,
    float* __restrict__ out)
{
    __shared__ float u_s[GPB * HIDDEN];    // 16 KB fp32 accumulator
    __shared__ short u_b[GPB * HIDDEN];    // 8 KB bf16, k XOR-swizzled per row
    __shared__ float red_s[8][GPB];        // 1 KB
    __shared__ int   offs_s[GPB + 1];

    const int t  = threadIdx.x;
    const int l  = t & 63;
    const int w  = t >> 6;                 // wave id 0..7
    const int g0 = blockIdx.x * GPB;

    // zero the fp32 accumulator (4096 floats = 1024 float4)
    float4* u_s4z = reinterpret_cast<float4*>(u_s);
    u_s4z[t]       = make_float4(0.f, 0.f, 0.f, 0.f);
    u_s4z[t + 512] = make_float4(0.f, 0.f, 0.f, 0.f);
    if (t < GPB + 1) offs_s[t] = offs[g0 + t];

    // ---- B-fragments: W1 cols [w*32, w*32+32), bf16, registers ----
    // frag[ct][kt]: lane l holds B[k = kt*32+(l>>4)*8+j][col = w*32+ct*16+(l&15)]
    short8 bfrag[2][4];
    {
        const int lcol = w * 32 + (l & 15);
        #pragma unroll
        for (int ct = 0; ct < 2; ++ct) {
            const int col = lcol + ct * 16;
            #pragma unroll
            for (int kt = 0; kt < 4; ++kt) {
                const int k0 = kt * 32 + (l >> 4) * 8;
                short8 f;
                #pragma unroll
                for (int j = 0; j < 8; ++j)
                    f[j] = (short)f2bf(W1[(size_t)(k0 + j) * 256 + col]);
                bfrag[ct][kt] = f;
            }
        }
    }
    __syncthreads();   // u_s zeroed + offs_s ready

    // ---------------- Phase 1: balanced-chunk segment-sum ----------------
    const float2* __restrict__ v2 = reinterpret_cast<const float2*>(v);
    const int blo = offs_s[0];
    const int bhi = offs_s[GPB];
    const int cs  = (bhi - blo + 7) >> 3;            // rows per wave chunk
    const int c0  = blo + w * cs;
    const int c1  = min(c0 + cs, bhi);

    if (c0 < c1) {
        // starting graph: largest cur in [0,31] with offs_s[cur] <= c0
        int cur = 0;
        #pragma unroll
        for (int step = 16; step >= 1; step >>= 1)
            if (cur + step <= 31 && offs_s[cur + step] <= c0) cur += step;
        int bnd = offs_s[cur + 1];
        float accx = 0.f, accy = 0.f;

        for (int r = c0; r < c1; r += 8) {
            float2 x[8];
            #pragma unroll
            for (int q = 0; q < 8; ++q) {
                int rq = r + q;
                rq = (rq < c1) ? rq : (c1 - 1);      // clamp tail (uniform)
                x[q] = v2[(size_t)rq * 64 + l];
            }
            #pragma unroll
            for (int q = 0; q < 8; ++q) {
                if (r + q < c1) {
                    while (r + q >= bnd) {           // graph boundary: flush run
                        atomicAdd(&u_s[cur * HIDDEN + 2 * l],     accx);
                        atomicAdd(&u_s[cur * HIDDEN + 2 * l + 1], accy);
                        accx = 0.f; accy = 0.f;
                        ++cur;
                        bnd = offs_s[cur + 1];       // cur <= 31
                    }
                    accx += x[q].x; accy += x[q].y;
                }
            }
        }
        // flush the final run
        atomicAdd(&u_s[cur * HIDDEN + 2 * l],     accx);
        atomicAdd(&u_s[cur * HIDDEN + 2 * l + 1], accy);
    }
    __syncthreads();

    // ---------------- convert u_s fp32 -> u_b bf16 (swizzled) ----------------
    {
        const int row = t >> 4;                      // 0..31
        const int e0  = (t & 15) * 8;                // 0..120
        const float4 lo4 = *reinterpret_cast<const float4*>(&u_s[row * HIDDEN + e0]);
        const float4 hi4 = *reinterpret_cast<const float4*>(&u_s[row * HIDDEN + e0 + 4]);
        short8 pk;
        pk[0] = (short)f2bf(lo4.x); pk[1] = (short)f2bf(lo4.y);
        pk[2] = (short)f2bf(lo4.z); pk[3] = (short)f2bf(lo4.w);
        pk[4] = (short)f2bf(hi4.x); pk[5] = (short)f2bf(hi4.y);
        pk[6] = (short)f2bf(hi4.z); pk[7] = (short)f2bf(hi4.w);
        *reinterpret_cast<short8*>(&u_b[row * HIDDEN + (e0 ^ ((row & 7) * 8))]) = pk;
    }
    __syncthreads();

    // ---------------- Phase 2: MFMA MLP (unchanged from R8) ----------------
    f32x4 acc[2][2];                       // [row-tile][col-tile]
    #pragma unroll
    for (int rt = 0; rt < 2; ++rt)
        #pragma unroll
        for (int ct = 0; ct < 2; ++ct)
            acc[rt][ct] = (f32x4){0.f, 0.f, 0.f, 0.f};

    #pragma unroll
    for (int kt = 0; kt < 4; ++kt) {
        #pragma unroll
        for (int rt = 0; rt < 2; ++rt) {
            const int row = rt * 16 + (l & 15);
            const int k0  = kt * 32 + (l >> 4) * 8;
            short8 a = *reinterpret_cast<const short8*>(
                &u_b[row * HIDDEN + (k0 ^ ((row & 7) * 8))]);
            #pragma unroll
            for (int ct = 0; ct < 2; ++ct)
                acc[rt][ct] = __builtin_amdgcn_mfma_f32_16x16x32_bf16(
                    a, bfrag[ct][kt], acc[rt][ct], 0, 0, 0);
        }
    }

    // epilogue: bias -> shifted softplus -> *W2 -> reduce 16 cols -> LDS
    float b1c[2], w2c[2];
    #pragma unroll
    for (int ct = 0; ct < 2; ++ct) {
        const int col = w * 32 + ct * 16 + (l & 15);
        b1c[ct] = b1[col];
        w2c[ct] = W2[col];
    }
    #pragma unroll
    for (int rt = 0; rt < 2; ++rt) {
        float p[4] = {0.f, 0.f, 0.f, 0.f};
        #pragma unroll
        for (int ct = 0; ct < 2; ++ct)
            #pragma unroll
            for (int reg = 0; reg < 4; ++reg) {
                float x = acc[rt][ct][reg] + b1c[ct];
                float h = fmaxf(x, 0.f) + log1pf(expf(-fabsf(x))) - kSHIFT;
                p[reg] = fmaf(h, w2c[ct], p[reg]);
            }
        #pragma unroll
        for (int reg = 0; reg < 4; ++reg) {
            float s = p[reg];
            s += __shfl_xor(s, 1);
            s += __shfl_xor(s, 2);
            s += __shfl_xor(s, 4);
            s += __shfl_xor(s, 8);
            if ((l & 15) == 0)
                red_s[w][rt * 16 + (l >> 4) * 4 + reg] = s;
        }
    }
    __syncthreads();

    if (t < GPB) {
        float s = (red_s[0][t] + red_s[1][t]) + (red_s[2][t] + red_s[3][t])
                + (red_s[4][t] + red_s[5][t]) + (red_s[6][t] + red_s[7][t]);
        out[g0 + t] = s + b2[0];
    }
}

extern "C" void kernel_launch(void* const* d_in, const int* in_sizes, int n_in,
                              void* d_out, int out_size, void* d_ws, size_t ws_size,
                              hipStream_t stream) {
    const float* v     = (const float*)d_in[0];
    const int*   batch = (const int*)d_in[1];
    const float* W1    = (const float*)d_in[2];
    const float* b1    = (const float*)d_in[3];
    const float* W2    = (const float*)d_in[4];
    const float* b2    = (const float*)d_in[5];
    float* out = (float*)d_out;

    const int n_nodes = in_sizes[0] / HIDDEN;   // 500000
    int* offs = (int*)d_ws;                     // (NGRAPH+1) ints

    offsets_kernel<<<(n_nodes + 255) / 256, 256, 0, stream>>>(batch, offs, n_nodes);
    fused_kernel<<<NBLK, NTHR, 0, stream>>>(v, offs, W1, b1, W2, b2, out);
}